// Round 13
// baseline (84.007 us; speedup 1.0000x reference)
//
#include <hip/hip_runtime.h>
#include <hip/hip_bf16.h>

typedef __attribute__((ext_vector_type(8))) short short8;
typedef __attribute__((ext_vector_type(4))) float f32x4;
typedef __attribute__((ext_vector_type(4))) unsigned u32x4;

#define LOG2E 1.44269504f
#define SCL2  0.18033688f   // 0.125 * log2(e)
#define MNEG  -3.0e38f

__device__ __forceinline__ short f2bf(float f) {
  union { float f; unsigned u; } x; x.f = f;
  return (short)((x.u + 0x7FFFu + ((x.u >> 16) & 1u)) >> 16);  // RNE
}
__device__ __forceinline__ float exp2g(float x) {
  float r; asm("v_exp_f32 %0, %1" : "=v"(r) : "v"(x)); return r;
}
__device__ __forceinline__ float log2g(float x) {
  float r; asm("v_log_f32 %0, %1" : "=v"(r) : "v"(x)); return r;
}
__device__ __forceinline__ unsigned cvt_pk_bf16(float lo, float hi) {
  unsigned r;
  asm("v_cvt_pk_bf16_f32 %0, %1, %2" : "=v"(r) : "v"(lo), "v"(hi));
  return r;
}

// ---------------- fused prepass: K conv x3 (pre-scaled by SCL2) | V^T | masks
__device__ __forceinline__ void conv_one(
    const float* __restrict__ src, short* __restrict__ dst,
    int Tin, int pad, int cid) {
  int Tpad = Tin + 2 * pad;
  int row = cid >> 3;
  int d0 = (cid & 7) * 8;
  int tok = row % Tpad;
  int nh = row / Tpad;
  int st = tok - pad;
  short8 o;
  if (st >= 0 && st < Tin) {
    const float4* sp = (const float4*)(src + ((size_t)nh * Tin + st) * 64 + d0);
    float4 f0 = sp[0], f1 = sp[1];
    o[0] = f2bf(f0.x * SCL2); o[1] = f2bf(f0.y * SCL2);
    o[2] = f2bf(f0.z * SCL2); o[3] = f2bf(f0.w * SCL2);
    o[4] = f2bf(f1.x * SCL2); o[5] = f2bf(f1.y * SCL2);
    o[6] = f2bf(f1.z * SCL2); o[7] = f2bf(f1.w * SCL2);
  } else {
#pragma unroll
    for (int j = 0; j < 8; ++j) o[j] = 0;
  }
  *(short8*)(dst + (size_t)row * 64 + d0) = o;
}

__device__ __forceinline__ void transv_one(
    const float* __restrict__ src, short* __restrict__ dst,
    int Tin, int pad, int tiles, int bidx, int tid, short (*lt)[72]) {
  int tile = bidx % tiles;
  int nh = bidx / tiles;
  int Tpad = Tin + 2 * pad;
  int c0 = tile * 64;
  int tok = tid >> 2;
  int dc = (tid & 3) * 16;
  int st = c0 + tok - pad;
  if (st >= 0 && st < Tin) {
    const float4* sp = (const float4*)(src + ((size_t)nh * Tin + st) * 64 + dc);
#pragma unroll
    for (int i = 0; i < 4; ++i) {
      float4 f = sp[i];
      lt[tok][dc + i * 4 + 0] = f2bf(f.x);
      lt[tok][dc + i * 4 + 1] = f2bf(f.y);
      lt[tok][dc + i * 4 + 2] = f2bf(f.z);
      lt[tok][dc + i * 4 + 3] = f2bf(f.w);
    }
  } else {
#pragma unroll
    for (int i = 0; i < 16; ++i) lt[tok][dc + i] = 0;
  }
  __syncthreads();
  int d = tid >> 2;
  int tc = (tid & 3) * 16;
  short8 o0, o1;
#pragma unroll
  for (int j = 0; j < 8; ++j) { o0[j] = lt[tc + j][d]; o1[j] = lt[tc + 8 + j][d]; }
  short* dp = dst + ((size_t)nh * 64 + d) * Tpad + c0 + tc;
  *(short8*)(dp) = o0;
  *(short8*)(dp + 8) = o1;
}

// block ranges: [0,3264) KL | +1008 KS | +48 KG | +1632 VTL | +504 VTS |
//               +24 VTG | +45 masks  => grid 6525
__global__ __launch_bounds__(256) void prepass_all(
    const float* __restrict__ K, const float* __restrict__ SK,
    const float* __restrict__ GK,
    const float* __restrict__ V, const float* __restrict__ SV,
    const float* __restrict__ GV,
    short* __restrict__ KL, short* __restrict__ KS, short* __restrict__ KG,
    short* __restrict__ VTL, short* __restrict__ VTS, short* __restrict__ VTG,
    const float* __restrict__ am, const float* __restrict__ sm,
    const float* __restrict__ gm,
    float* __restrict__ AM2, float* __restrict__ SM2, float* __restrict__ GM2) {
  __shared__ short lt[64][72];
  int bidx = blockIdx.x;
  int tid = threadIdx.x;
  if (bidx < 3264) { conv_one(K,  KL, 4096, 128, bidx * 256 + tid); return; }
  bidx -= 3264;
  if (bidx < 1008) { conv_one(SK, KS, 1024, 160, bidx * 256 + tid); return; }
  bidx -= 1008;
  if (bidx < 48)   { conv_one(GK, KG, 64, 0, bidx * 256 + tid); return; }
  bidx -= 48;
  if (bidx < 1632) { transv_one(V,  VTL, 4096, 128, 68, bidx, tid, lt); return; }
  bidx -= 1632;
  if (bidx < 504)  { transv_one(SV, VTS, 1024, 160, 21, bidx, tid, lt); return; }
  bidx -= 504;
  if (bidx < 24)   { transv_one(GV, VTG, 64, 0, 1, bidx, tid, lt); return; }
  bidx -= 24;
  int i = bidx * 256 + tid;   // mask work: 11520 elements exactly
  if (i < 2 * 4352) {
    int n = i / 4352, rr = i % 4352, s = rr - 128;
    AM2[i] = (s >= 0 && s < 4096) ? am[n * 4096 + s] * LOG2E : MNEG;
  } else if (i < 2 * 4352 + 2 * 1344) {
    int j = i - 2 * 4352;
    int n = j / 1344, rr = j % 1344, s = rr - 160;
    SM2[j] = (s >= 0 && s < 1024) ? sm[n * 1024 + s] * LOG2E : MNEG;
  } else {
    int j = i - 2 * 4352 - 2 * 1344;
    GM2[j] = gm[j] * LOG2E;
  }
}

// ---------------- main attention kernel (4 waves x 32q, swapped QK^T) -------
// 256 threads / 4 waves; wave w owns queries [w*32, w*32+32) as two 16-row
// groups mt=0,1. Swapped QK^T mfma(K,Q); K pre-scaled by SCL2; mask is the
// MFMA C-operand. K staged with bit-permuted row map so each lane's P values
// are its own PV A-fragment (in-register P). Softmax: per-lane partial (16
// keys of query c); mrun init 0; rare MULTIPLICATIVE rescale (no score
// retention): sc = 1/max(rowsum,1), p*=sc, mrun+=log2 — query-consistent via
// 2 shfls in the branch only. bv read once feeds both mt -> per-CU LDS
// traffic ~halved vs 8-wave (round-11 bottleneck: LDS pipe ~48% busy).
// Staging: each wave writes 8 rows x 8 chunks twice (proven conflict-free).
// K/V LDS: [64 rows][128 B], byte = row*128 + (col16 ^ ((row&7)<<4)).
// Tile liveness: t1:b>=4 | t2:b>=2 | t3:b<=29 | t4:b<=27 | t5,t6:b>=1 |
// t7,t8 always | t9,t10: b<=30.
__global__ __launch_bounds__(256, 3) void lsg_attn11(
    const short* __restrict__ KL, const short* __restrict__ VTL,
    const short* __restrict__ KS, const short* __restrict__ VTS,
    const short* __restrict__ KG, const short* __restrict__ VTG,
    const float* __restrict__ AM2, const float* __restrict__ SM2,
    const float* __restrict__ GM2,
    const float* __restrict__ q_, float* __restrict__ out) {
  constexpr int TPL = 4352, TPS = 1344;
  __shared__ __align__(16) char smem[35328];  // K dbuf 16K | V dbuf 16K | scl 512B

  int bid = blockIdx.x;
  bid = (bid & 7) * 96 + (bid >> 3);        // XCD-contiguous logical ids
  const int b = bid & 31, nh = bid >> 5, n_ = nh / 12;
  const int tid = threadIdx.x;
  const int wid = tid >> 6, lane = tid & 63;
  const int c = lane & 15, g = lane >> 4;
  // staging: wave writes rows [wid*8, +8) and [32+wid*8, +8), 8 chunks each
  const int rl = lane >> 3, ch = lane & 7;
  const int row0 = wid * 8 + rl, row1 = row0 + 32;
  auto perm = [](int r) {   // [kt1][g1 g0][kt0][j1 j0]
    return ((r >> 5) << 5) | (((r >> 2) & 3) << 3) |
           (((r >> 4) & 1) << 2) | (r & 3);
  };
  const int skey0 = perm(row0), skey1 = perm(row1);
  float* sclw = (float*)(smem + 32768) + wid * 32;
  const unsigned stg0 = ((unsigned)row0 << 7) +
                        ((unsigned)(ch * 16) ^ ((unsigned)(row0 & 7) << 4));
  const unsigned stg1 = ((unsigned)row1 << 7) +
                        ((unsigned)(ch * 16) ^ ((unsigned)(row1 & 7) << 4));

  // ---- tile list: live tiles only, 4 bits per entry ----
  unsigned long long enc = 0; int nt = 0;
  {
    auto push = [&](int t) { enc |= (unsigned long long)t << (4 * nt); ++nt; };
    push(0);
    if (b >= 4)  push(1);
    if (b >= 2)  push(2);
    if (b <= 29) push(3);
    if (b <= 27) push(4);
    if (b >= 1)  { push(5); push(6); }
    push(7); push(8);
    if (b <= 30) { push(9); push(10); }
  }

  // ---- Q fragments: wave's 32 rows (two 16-row groups) ----
  const float* qb = q_ + ((size_t)nh * 4096 + (size_t)b * 128 + wid * 32) * 64;
  short8 qa[2][2];
#pragma unroll
  for (int mt = 0; mt < 2; ++mt)
#pragma unroll
    for (int kc = 0; kc < 2; ++kc) {
      const float* qp = qb + (size_t)(mt * 16 + c) * 64 + kc * 32 + g * 8;
      float4 f0 = *(const float4*)(qp);
      float4 f1 = *(const float4*)(qp + 4);
      short8 tq;
      tq[0] = f2bf(f0.x); tq[1] = f2bf(f0.y); tq[2] = f2bf(f0.z); tq[3] = f2bf(f0.w);
      tq[4] = f2bf(f1.x); tq[5] = f2bf(f1.y); tq[6] = f2bf(f1.z); tq[7] = f2bf(f1.w);
      qa[mt][kc] = tq;
    }

  f32x4 acc[2][4];
#pragma unroll
  for (int mt = 0; mt < 2; ++mt)
#pragma unroll
    for (int dd = 0; dd < 4; ++dd) acc[mt][dd] = f32x4{0.f, 0.f, 0.f, 0.f};
  float mrun[2] = {0.f, 0.f}, lrun[2] = {0.f, 0.f};

  auto src_for = [&](int t, const short*& kp, const short*& vp,
                     const float*& mp, int& stride) {
    if (t == 0) {
      kp = KG + (size_t)nh * (64 * 64);
      vp = VTG + (size_t)nh * (64 * 64);
      mp = GM2 + n_ * 64;
      stride = 64;
    } else if (t <= 4) {
      int r0 = b * 32 + (t - 1) * 64 + (t >= 3 ? 96 : 0);
      kp = KS + ((size_t)nh * TPS + r0) * 64;
      vp = VTS + (size_t)nh * (64 * TPS) + r0;
      mp = SM2 + n_ * TPS + r0;
      stride = TPS;
    } else {
      int r0 = b * 128 + (t - 5) * 64;
      kp = KL + ((size_t)nh * TPL + r0) * 64;
      vp = VTL + (size_t)nh * (64 * TPL) + r0;
      mp = AM2 + n_ * TPL + r0;
      stride = TPL;
    }
  };

  short8 kr0, kr1, vr0, vr1;

  // ---- prologue: tile[0] -> buf0; tile[1] -> regs ----
  {
    const short* kp; const short* vp; const float* mp; int st;
    src_for(0, kp, vp, mp, st);
    kr0 = *(const short8*)(kp + skey0 * 64 + ch * 8);
    kr1 = *(const short8*)(kp + skey1 * 64 + ch * 8);
    vr0 = *(const short8*)(vp + (size_t)row0 * st + ch * 8);
    vr1 = *(const short8*)(vp + (size_t)row1 * st + ch * 8);
    *(short8*)(smem + stg0) = kr0;
    *(short8*)(smem + stg1) = kr1;
    *(short8*)(smem + 16384 + stg0) = vr0;
    *(short8*)(smem + 16384 + stg1) = vr1;
    src_for((int)((enc >> 4) & 15ull), kp, vp, mp, st);   // nt >= 7 always
    kr0 = *(const short8*)(kp + skey0 * 64 + ch * 8);
    kr1 = *(const short8*)(kp + skey1 * 64 + ch * 8);
    vr0 = *(const short8*)(vp + (size_t)row0 * st + ch * 8);
    vr1 = *(const short8*)(vp + (size_t)row1 * st + ch * 8);
  }

  for (int i = 0; i < nt; ++i) {
    // own LDS ops drained, then workgroup barrier; vmcnt NOT drained
    asm volatile("s_waitcnt lgkmcnt(0)\n\ts_barrier" ::: "memory");
    const int cur = i & 1, nxt = cur ^ 1;
    char* kbuf = smem + cur * 8192;
    char* vbuf = smem + 16384 + cur * 8192;

    // ---- current tile's mask fragments (MFMA C-operands) ----
    // lane (c,g) holds keys (kt>>1)*32 + g*8 + (kt&1)*4 + j
    f32x4 mk[4];
    {
      int tl = (int)((enc >> (4 * i)) & 15ull);
      const short* kp; const short* vp; const float* mp; int st;
      src_for(tl, kp, vp, mp, st);
#pragma unroll
      for (int kt = 0; kt < 4; ++kt)
        mk[kt] = *(const f32x4*)(mp + ((kt >> 1) << 5) + g * 8 + ((kt & 1) << 2));
    }

    // ---- QK^T swapped, per-kt bk lifetime; mask as C-in; scores -> p ----
    f32x4 p40[4], p41[4];
    __builtin_amdgcn_s_setprio(1);
#pragma unroll
    for (int kt = 0; kt < 4; ++kt) {
      unsigned off0 = ((unsigned)(kt * 16 + c) << 7) +
                      ((unsigned)(g * 16) ^ ((unsigned)(c & 7) << 4));
      unsigned off1 = ((unsigned)(kt * 16 + c) << 7) +
                      ((unsigned)(64 + g * 16) ^ ((unsigned)(c & 7) << 4));
      short8 bk0 = *(const short8*)(kbuf + off0);
      short8 bk1 = *(const short8*)(kbuf + off1);
      f32x4 z0 = __builtin_amdgcn_mfma_f32_16x16x32_bf16(bk0, qa[0][0], mk[kt], 0, 0, 0);
      z0 = __builtin_amdgcn_mfma_f32_16x16x32_bf16(bk1, qa[0][1], z0, 0, 0, 0);
      p40[kt] = z0;
      f32x4 z1 = __builtin_amdgcn_mfma_f32_16x16x32_bf16(bk0, qa[1][0], mk[kt], 0, 0, 0);
      z1 = __builtin_amdgcn_mfma_f32_16x16x32_bf16(bk1, qa[1][1], z1, 0, 0, 0);
      p41[kt] = z1;
    }
    __builtin_amdgcn_s_setprio(0);

    // ---- write staged tile[i+1]; prefetch tile[i+2] ----
    if (i + 1 < nt) {
      *(short8*)(smem + nxt * 8192 + stg0) = kr0;
      *(short8*)(smem + nxt * 8192 + stg1) = kr1;
      *(short8*)(smem + 16384 + nxt * 8192 + stg0) = vr0;
      *(short8*)(smem + 16384 + nxt * 8192 + stg1) = vr1;
    }
    if (i + 2 < nt) {
      int tn = (int)((enc >> (4 * (i + 2))) & 15ull);
      const short* kp; const short* vp; const float* mp; int st;
      src_for(tn, kp, vp, mp, st);
      kr0 = *(const short8*)(kp + skey0 * 64 + ch * 8);
      kr1 = *(const short8*)(kp + skey1 * 64 + ch * 8);
      vr0 = *(const short8*)(vp + (size_t)row0 * st + ch * 8);
      vr1 = *(const short8*)(vp + (size_t)row1 * st + ch * 8);
    }

    // ---- softmax: exp in place (optimistic), per-lane partial sums ----
    float rs0 = 0.f, rs1 = 0.f;
#pragma unroll
    for (int kt = 0; kt < 4; ++kt)
#pragma unroll
      for (int j = 0; j < 4; ++j) {
        float p0 = exp2g(p40[kt][j] - mrun[0]);
        float p1 = exp2g(p41[kt][j] - mrun[1]);
        p40[kt][j] = p0; rs0 += p0;
        p41[kt][j] = p1; rs1 += p1;
      }

    if (__any(fmaxf(rs0, rs1) > 1024.f)) {  // first tile + rare genuine growth
#pragma unroll
      for (int mt = 0; mt < 2; ++mt) {
        f32x4* p4 = mt ? p41 : p40;
        float rs = mt ? rs1 : rs0;
        float tot = rs;
        tot += __shfl_xor(tot, 16);
        tot += __shfl_xor(tot, 32);          // full row sum for query c
        float rsc = fmaxf(tot, 1.0f);
        float sc = 1.0f / rsc;               // uniform across query's lanes
        mrun[mt] += log2g(rsc);
#pragma unroll
        for (int kt = 0; kt < 4; ++kt) p4[kt] *= sc;
        lrun[mt] = lrun[mt] * sc + rs * sc;
        if (lane < 16) sclw[mt * 16 + lane] = sc;
      }
      // acc rescale needs per-query sc in D-layout (row = 4g+j)
      asm volatile("s_waitcnt lgkmcnt(0)" ::: "memory");
#pragma unroll
      for (int mt = 0; mt < 2; ++mt) {
        f32x4 sq = *(const f32x4*)&sclw[mt * 16 + 4 * g];
#pragma unroll
        for (int dd = 0; dd < 4; ++dd)
#pragma unroll
          for (int j = 0; j < 4; ++j) acc[mt][dd][j] *= sq[j];
      }
    } else {
      lrun[0] += rs0;
      lrun[1] += rs1;
    }

    // ---- pack P (own regs) and PV: bv read once, feeds both mt ----
#pragma unroll
    for (int kk = 0; kk < 2; ++kk) {
      u32x4 u0, u1;
      u0[0] = cvt_pk_bf16(p40[2 * kk][0], p40[2 * kk][1]);
      u0[1] = cvt_pk_bf16(p40[2 * kk][2], p40[2 * kk][3]);
      u0[2] = cvt_pk_bf16(p40[2 * kk + 1][0], p40[2 * kk + 1][1]);
      u0[3] = cvt_pk_bf16(p40[2 * kk + 1][2], p40[2 * kk + 1][3]);
      u1[0] = cvt_pk_bf16(p41[2 * kk][0], p41[2 * kk][1]);
      u1[1] = cvt_pk_bf16(p41[2 * kk][2], p41[2 * kk][3]);
      u1[2] = cvt_pk_bf16(p41[2 * kk + 1][0], p41[2 * kk + 1][1]);
      u1[3] = cvt_pk_bf16(p41[2 * kk + 1][2], p41[2 * kk + 1][3]);
      short8 pa0 = __builtin_bit_cast(short8, u0);
      short8 pa1 = __builtin_bit_cast(short8, u1);
      __builtin_amdgcn_s_setprio(1);
#pragma unroll
      for (int dd = 0; dd < 4; ++dd) {
        unsigned voff = ((unsigned)(dd * 16 + c) << 7) +
                        ((unsigned)(kk * 64 + g * 16) ^ ((unsigned)(c & 7) << 4));
        short8 bv = *(const short8*)(vbuf + voff);
        acc[0][dd] = __builtin_amdgcn_mfma_f32_16x16x32_bf16(pa0, bv, acc[0][dd], 0, 0, 0);
        acc[1][dd] = __builtin_amdgcn_mfma_f32_16x16x32_bf16(pa1, bv, acc[1][dd], 0, 0, 0);
      }
      __builtin_amdgcn_s_setprio(0);
    }
  }

  // ---- epilogue: reduce l over key-groups, redistribute, store ----
  f32x4 iv[2];
#pragma unroll
  for (int mt = 0; mt < 2; ++mt) {
    float l = lrun[mt];
    l += __shfl_xor(l, 16);
    l += __shfl_xor(l, 32);
    if (lane < 16) sclw[mt * 16 + lane] = 1.f / l;
  }
  __syncthreads();
#pragma unroll
  for (int mt = 0; mt < 2; ++mt)
    iv[mt] = *(const f32x4*)&sclw[mt * 16 + 4 * g];
  __syncthreads();   // iv read everywhere -> LDS reusable as fp32 staging
  float* fst = (float*)smem + wid * (32 * 68);   // per-wave [32][68] fp32
#pragma unroll
  for (int mt = 0; mt < 2; ++mt)
#pragma unroll
    for (int j = 0; j < 4; ++j)
#pragma unroll
      for (int dd = 0; dd < 4; ++dd)
        fst[(mt * 16 + 4 * g + j) * 68 + dd * 16 + c] = acc[mt][dd][j] * iv[mt][j];
  int rr = lane >> 1, hh = lane & 1;
  const float* fs = fst + rr * 68 + hh * 32;
  float* op = out + ((size_t)nh * 4096 + (size_t)b * 128 + wid * 32 + rr) * 64 + hh * 32;
#pragma unroll
  for (int i = 0; i < 8; ++i)
    *(float4*)(op + i * 4) = *(const float4*)(fs + i * 4);
}

// ---------------- fallback (round-1 kernel, used if ws too small) -----------
__global__ __launch_bounds__(256) void lsg_attn_fb(
    const float* __restrict__ q_,  const float* __restrict__ k_,
    const float* __restrict__ v_,  const float* __restrict__ amask,
    const float* __restrict__ sk,  const float* __restrict__ sv,
    const float* __restrict__ smk, const float* __restrict__ gk,
    const float* __restrict__ gv,  const float* __restrict__ gmk,
    float* __restrict__ out) {
  constexpr int T = 4096, D = 64, TS = 1024;
  constexpr float NEGF = -3.402823466e38f;
  __shared__ __align__(16) short k_lds[32][72];
  __shared__ __align__(16) short v_lds[64][40];
  __shared__ __align__(16) short p_lds[4][32][40];
  __shared__ float m_lds[32];
  const int bid = blockIdx.x;
  const int b = bid & 31, nh = bid >> 5, n_ = nh / 12;
  const int tid = threadIdx.x, wid = tid >> 6, lane = tid & 63;
  const int c = lane & 15, g = lane >> 4;
  const float* qb = q_ + ((size_t)nh * T + (size_t)b * 128) * D;
  const float* kb = k_ + (size_t)nh * T * D;
  const float* vb = v_ + (size_t)nh * T * D;
  const float* skb = sk + (size_t)nh * TS * D;
  const float* svb = sv + (size_t)nh * TS * D;
  const float* gkb = gk + (size_t)nh * 64 * D;
  const float* gvb = gv + (size_t)nh * 64 * D;
  const float* am = amask + (size_t)n_ * T;
  const float* sm = smk + (size_t)n_ * TS;
  const float* gm = gmk + (size_t)n_ * 64;
  short8 qa[2][2];
#pragma unroll
  for (int mt = 0; mt < 2; ++mt)
#pragma unroll
    for (int kc = 0; kc < 2; ++kc) {
      const float* qp = qb + (size_t)(wid * 32 + mt * 16 + c) * D + kc * 32 + g * 8;
      short8 t;
#pragma unroll
      for (int j = 0; j < 8; ++j) t[j] = f2bf(qp[j]);
      qa[mt][kc] = t;
    }
  f32x4 acc[2][4];
#pragma unroll
  for (int mt = 0; mt < 2; ++mt)
#pragma unroll
    for (int dd = 0; dd < 4; ++dd) acc[mt][dd] = f32x4{0.f, 0.f, 0.f, 0.f};
  float mrun[2][4], lrun[2][4];
#pragma unroll
  for (int mt = 0; mt < 2; ++mt)
#pragma unroll
    for (int j = 0; j < 4; ++j) { mrun[mt][j] = NEGF; lrun[mt][j] = 0.f; }
  const int key_local = tid >> 3;
  const int seg = tid & 7;
  const int d0 = seg * 8;
  for (int tile = 0; tile < 22; ++tile) {
    __syncthreads();
    {
      const int kk = tile * 32 + key_local;
      const float* ksrc; const float* vsrc; float mval; bool valid;
      if (kk < 64) {
        ksrc = gkb + kk * D; vsrc = gvb + kk * D; mval = gm[kk]; valid = true;
      } else if (kk < 320) {
        int s = b * 32 - 160 + (kk - 64) + ((kk >= 192) ? 96 : 0);
        valid = (s >= 0) && (s < TS);
        int sc2 = valid ? s : 0;
        ksrc = skb + sc2 * D; vsrc = svb + sc2 * D;
        mval = valid ? sm[sc2] : NEGF;
      } else {
        int tt = b * 128 - 128 + (kk - 320);
        valid = (tt >= 0) && (tt < T);
        int tc = valid ? tt : 0;
        ksrc = kb + tc * D; vsrc = vb + tc * D;
        mval = valid ? am[tc] : NEGF;
      }
      short8 k8; short v8[8];
      if (valid) {
#pragma unroll
        for (int j = 0; j < 8; ++j) { k8[j] = f2bf(ksrc[d0 + j]); v8[j] = f2bf(vsrc[d0 + j]); }
      } else {
#pragma unroll
        for (int j = 0; j < 8; ++j) { k8[j] = 0; v8[j] = 0; }
      }
      *(short8*)(&k_lds[key_local][d0]) = k8;
#pragma unroll
      for (int j = 0; j < 8; ++j) v_lds[d0 + j][key_local] = v8[j];
      if (seg == 0) m_lds[key_local] = mval;
    }
    __syncthreads();
    short8 bk[2][2];
#pragma unroll
    for (int kt = 0; kt < 2; ++kt)
#pragma unroll
      for (int kc = 0; kc < 2; ++kc)
        bk[kt][kc] = *(const short8*)(&k_lds[kt * 16 + c][kc * 32 + g * 8]);
    f32x4 s_[2][2];
#pragma unroll
    for (int mt = 0; mt < 2; ++mt)
#pragma unroll
      for (int kt = 0; kt < 2; ++kt) {
        f32x4 z = f32x4{0.f, 0.f, 0.f, 0.f};
        z = __builtin_amdgcn_mfma_f32_16x16x32_bf16(qa[mt][0], bk[kt][0], z, 0, 0, 0);
        z = __builtin_amdgcn_mfma_f32_16x16x32_bf16(qa[mt][1], bk[kt][1], z, 0, 0, 0);
        s_[mt][kt] = z;
      }
    const float msk0 = m_lds[c];
    const float msk1 = m_lds[16 + c];
#pragma unroll
    for (int mt = 0; mt < 2; ++mt) {
#pragma unroll
      for (int j = 0; j < 4; ++j) {
        float s0 = s_[mt][0][j] * 0.125f + msk0;
        float s1 = s_[mt][1][j] * 0.125f + msk1;
        float tv = fmaxf(s0, s1);
        tv = fmaxf(tv, __shfl_xor(tv, 1));
        tv = fmaxf(tv, __shfl_xor(tv, 2));
        tv = fmaxf(tv, __shfl_xor(tv, 4));
        tv = fmaxf(tv, __shfl_xor(tv, 8));
        float mold = mrun[mt][j];
        float mnew = fmaxf(mold, tv);
        float scale = __expf(mold - mnew);
        mrun[mt][j] = mnew;
        float p0 = __expf(s0 - mnew);
        float p1 = __expf(s1 - mnew);
        lrun[mt][j] = lrun[mt][j] * scale + p0 + p1;
#pragma unroll
        for (int dd = 0; dd < 4; ++dd) acc[mt][dd][j] *= scale;
        p_lds[wid][mt * 16 + g * 4 + j][c] = f2bf(p0);
        p_lds[wid][mt * 16 + g * 4 + j][16 + c] = f2bf(p1);
      }
    }
    __syncthreads();
#pragma unroll
    for (int mt = 0; mt < 2; ++mt) {
      short8 pa = *(const short8*)(&p_lds[wid][mt * 16 + c][g * 8]);
#pragma unroll
      for (int dd = 0; dd < 4; ++dd) {
        short8 bv = *(const short8*)(&v_lds[dd * 16 + c][g * 8]);
        acc[mt][dd] = __builtin_amdgcn_mfma_f32_16x16x32_bf16(pa, bv, acc[mt][dd], 0, 0, 0);
      }
    }
  }
  float* ob = out + ((size_t)nh * T + (size_t)b * 128 + (size_t)wid * 32) * D;
#pragma unroll
  for (int mt = 0; mt < 2; ++mt)
#pragma unroll
    for (int j = 0; j < 4; ++j) {
      float l = lrun[mt][j];
      l += __shfl_xor(l, 1);
      l += __shfl_xor(l, 2);
      l += __shfl_xor(l, 4);
      l += __shfl_xor(l, 8);
      float inv = 1.f / l;
      int row = mt * 16 + g * 4 + j;
#pragma unroll
      for (int dd = 0; dd < 4; ++dd)
        ob[(size_t)row * D + dd * 16 + c] = acc[mt][dd][j] * inv;
    }
}

extern "C" void kernel_launch(void* const* d_in, const int* in_sizes, int n_in,
                              void* d_out, int out_size, void* d_ws, size_t ws_size,
                              hipStream_t stream) {
  const float* q  = (const float*)d_in[0];
  const float* k  = (const float*)d_in[1];
  const float* v  = (const float*)d_in[2];
  const float* am = (const float*)d_in[3];
  const float* sk = (const float*)d_in[4];
  const float* sv = (const float*)d_in[5];
  const float* sm = (const float*)d_in[6];
  const float* gk = (const float*)d_in[7];
  const float* gv = (const float*)d_in[8];
  const float* gm = (const float*)d_in[9];
  float* out = (float*)d_out;

  size_t off = 0;
  char* base = (char*)d_ws;
  auto alloc = [&](size_t bytes) { void* p = base + off; off += bytes; return p; };
  short* KL  = (short*)alloc(13369344);  // [24][4352][64] bf16 (pre-scaled)
  short* VTL = (short*)alloc(13369344);  // [24][64][4352]
  short* KS  = (short*)alloc(4128768);   // [24][1344][64]
  short* VTS = (short*)alloc(4128768);   // [24][64][1344]
  short* KG  = (short*)alloc(196608);    // [24][64][64]
  short* VTG = (short*)alloc(196608);    // [24][64][64]
  float* AM2 = (float*)alloc(34816);     // [2][4352]
  float* SM2 = (float*)alloc(10752);     // [2][1344]
  float* GM2 = (float*)alloc(512);       // [2][64]

  if (off <= ws_size) {
    hipLaunchKernelGGL(prepass_all, dim3(6525), dim3(256), 0, stream,
                       k, sk, gk, v, sv, gv, KL, KS, KG, VTL, VTS, VTG,
                       am, sm, gm, AM2, SM2, GM2);
    hipLaunchKernelGGL(lsg_attn11, dim3(768), dim3(256), 0, stream,
                       KL, VTL, KS, VTS, KG, VTG, AM2, SM2, GM2, q, out);
  } else {
    hipLaunchKernelGGL(lsg_attn_fb, dim3(768), dim3(256), 0, stream,
                       q, k, v, am, sk, sv, sm, gk, gv, gm, out);
  }
}

// Round 14
// 74.169 us; speedup vs baseline: 1.1326x; 1.1326x over previous
//
#include <hip/hip_runtime.h>
#include <hip/hip_bf16.h>

typedef __attribute__((ext_vector_type(8))) short short8;
typedef __attribute__((ext_vector_type(4))) float f32x4;
typedef __attribute__((ext_vector_type(4))) unsigned u32x4;

#define LOG2E 1.44269504f
#define SCL2  0.18033688f   // 0.125 * log2(e)
#define MNEG  -3.0e38f

__device__ __forceinline__ short f2bf(float f) {
  union { float f; unsigned u; } x; x.f = f;
  return (short)((x.u + 0x7FFFu + ((x.u >> 16) & 1u)) >> 16);  // RNE
}
__device__ __forceinline__ float exp2g(float x) {
  float r; asm("v_exp_f32 %0, %1" : "=v"(r) : "v"(x)); return r;
}
__device__ __forceinline__ float log2g(float x) {
  float r; asm("v_log_f32 %0, %1" : "=v"(r) : "v"(x)); return r;
}
__device__ __forceinline__ unsigned cvt_pk_bf16(float lo, float hi) {
  unsigned r;
  asm("v_cvt_pk_bf16_f32 %0, %1, %2" : "=v"(r) : "v"(lo), "v"(hi));
  return r;
}

// ---------------- fused prepass: K conv x3 (pre-scaled by SCL2) | V^T | masks
__device__ __forceinline__ void conv_one(
    const float* __restrict__ src, short* __restrict__ dst,
    int Tin, int pad, int cid) {
  int Tpad = Tin + 2 * pad;
  int row = cid >> 3;
  int d0 = (cid & 7) * 8;
  int tok = row % Tpad;
  int nh = row / Tpad;
  int st = tok - pad;
  short8 o;
  if (st >= 0 && st < Tin) {
    const float4* sp = (const float4*)(src + ((size_t)nh * Tin + st) * 64 + d0);
    float4 f0 = sp[0], f1 = sp[1];
    o[0] = f2bf(f0.x * SCL2); o[1] = f2bf(f0.y * SCL2);
    o[2] = f2bf(f0.z * SCL2); o[3] = f2bf(f0.w * SCL2);
    o[4] = f2bf(f1.x * SCL2); o[5] = f2bf(f1.y * SCL2);
    o[6] = f2bf(f1.z * SCL2); o[7] = f2bf(f1.w * SCL2);
  } else {
#pragma unroll
    for (int j = 0; j < 8; ++j) o[j] = 0;
  }
  *(short8*)(dst + (size_t)row * 64 + d0) = o;
}

__device__ __forceinline__ void transv_one(
    const float* __restrict__ src, short* __restrict__ dst,
    int Tin, int pad, int tiles, int bidx, int tid, short (*lt)[72]) {
  int tile = bidx % tiles;
  int nh = bidx / tiles;
  int Tpad = Tin + 2 * pad;
  int c0 = tile * 64;
  int tok = tid >> 2;
  int dc = (tid & 3) * 16;
  int st = c0 + tok - pad;
  if (st >= 0 && st < Tin) {
    const float4* sp = (const float4*)(src + ((size_t)nh * Tin + st) * 64 + dc);
#pragma unroll
    for (int i = 0; i < 4; ++i) {
      float4 f = sp[i];
      lt[tok][dc + i * 4 + 0] = f2bf(f.x);
      lt[tok][dc + i * 4 + 1] = f2bf(f.y);
      lt[tok][dc + i * 4 + 2] = f2bf(f.z);
      lt[tok][dc + i * 4 + 3] = f2bf(f.w);
    }
  } else {
#pragma unroll
    for (int i = 0; i < 16; ++i) lt[tok][dc + i] = 0;
  }
  __syncthreads();
  int d = tid >> 2;
  int tc = (tid & 3) * 16;
  short8 o0, o1;
#pragma unroll
  for (int j = 0; j < 8; ++j) { o0[j] = lt[tc + j][d]; o1[j] = lt[tc + 8 + j][d]; }
  short* dp = dst + ((size_t)nh * 64 + d) * Tpad + c0 + tc;
  *(short8*)(dp) = o0;
  *(short8*)(dp + 8) = o1;
}

// block ranges: [0,3264) KL | +1008 KS | +48 KG | +1632 VTL | +504 VTS |
//               +24 VTG | +45 masks  => grid 6525
__global__ __launch_bounds__(256) void prepass_all(
    const float* __restrict__ K, const float* __restrict__ SK,
    const float* __restrict__ GK,
    const float* __restrict__ V, const float* __restrict__ SV,
    const float* __restrict__ GV,
    short* __restrict__ KL, short* __restrict__ KS, short* __restrict__ KG,
    short* __restrict__ VTL, short* __restrict__ VTS, short* __restrict__ VTG,
    const float* __restrict__ am, const float* __restrict__ sm,
    const float* __restrict__ gm,
    float* __restrict__ AM2, float* __restrict__ SM2, float* __restrict__ GM2) {
  __shared__ short lt[64][72];
  int bidx = blockIdx.x;
  int tid = threadIdx.x;
  if (bidx < 3264) { conv_one(K,  KL, 4096, 128, bidx * 256 + tid); return; }
  bidx -= 3264;
  if (bidx < 1008) { conv_one(SK, KS, 1024, 160, bidx * 256 + tid); return; }
  bidx -= 1008;
  if (bidx < 48)   { conv_one(GK, KG, 64, 0, bidx * 256 + tid); return; }
  bidx -= 48;
  if (bidx < 1632) { transv_one(V,  VTL, 4096, 128, 68, bidx, tid, lt); return; }
  bidx -= 1632;
  if (bidx < 504)  { transv_one(SV, VTS, 1024, 160, 21, bidx, tid, lt); return; }
  bidx -= 504;
  if (bidx < 24)   { transv_one(GV, VTG, 64, 0, 1, bidx, tid, lt); return; }
  bidx -= 24;
  int i = bidx * 256 + tid;   // mask work: 11520 elements exactly
  if (i < 2 * 4352) {
    int n = i / 4352, rr = i % 4352, s = rr - 128;
    AM2[i] = (s >= 0 && s < 4096) ? am[n * 4096 + s] * LOG2E : MNEG;
  } else if (i < 2 * 4352 + 2 * 1344) {
    int j = i - 2 * 4352;
    int n = j / 1344, rr = j % 1344, s = rr - 160;
    SM2[j] = (s >= 0 && s < 1024) ? sm[n * 1024 + s] * LOG2E : MNEG;
  } else {
    int j = i - 2 * 4352 - 2 * 1344;
    GM2[j] = gm[j] * LOG2E;
  }
}

// ---------------- main attention kernel (4 waves x 32q, swapped QK^T) -------
// As round 13 but with rule-#20 fix: NO address-taken local arrays (the
// `p4 = mt ? p41 : p40` pointer demoted p40/p41 to scratch -> 151MB WRITE).
// Rescale branch hand-unrolled with named arrays only.
__global__ __launch_bounds__(256, 3) void lsg_attn12(
    const short* __restrict__ KL, const short* __restrict__ VTL,
    const short* __restrict__ KS, const short* __restrict__ VTS,
    const short* __restrict__ KG, const short* __restrict__ VTG,
    const float* __restrict__ AM2, const float* __restrict__ SM2,
    const float* __restrict__ GM2,
    const float* __restrict__ q_, float* __restrict__ out) {
  constexpr int TPL = 4352, TPS = 1344;
  __shared__ __align__(16) char smem[35328];  // K dbuf 16K | V dbuf 16K | scl 512B

  int bid = blockIdx.x;
  bid = (bid & 7) * 96 + (bid >> 3);        // XCD-contiguous logical ids
  const int b = bid & 31, nh = bid >> 5, n_ = nh / 12;
  const int tid = threadIdx.x;
  const int wid = tid >> 6, lane = tid & 63;
  const int c = lane & 15, g = lane >> 4;
  // staging: wave writes rows [wid*8, +8) and [32+wid*8, +8), 8 chunks each
  const int rl = lane >> 3, ch = lane & 7;
  const int row0 = wid * 8 + rl, row1 = row0 + 32;
  auto perm = [](int r) {   // [kt1][g1 g0][kt0][j1 j0]
    return ((r >> 5) << 5) | (((r >> 2) & 3) << 3) |
           (((r >> 4) & 1) << 2) | (r & 3);
  };
  const int skey0 = perm(row0), skey1 = perm(row1);
  float* sclw = (float*)(smem + 32768) + wid * 32;
  const unsigned stg0 = ((unsigned)row0 << 7) +
                        ((unsigned)(ch * 16) ^ ((unsigned)(row0 & 7) << 4));
  const unsigned stg1 = ((unsigned)row1 << 7) +
                        ((unsigned)(ch * 16) ^ ((unsigned)(row1 & 7) << 4));

  // ---- tile list: live tiles only, 4 bits per entry ----
  unsigned long long enc = 0; int nt = 0;
  {
    auto push = [&](int t) { enc |= (unsigned long long)t << (4 * nt); ++nt; };
    push(0);
    if (b >= 4)  push(1);
    if (b >= 2)  push(2);
    if (b <= 29) push(3);
    if (b <= 27) push(4);
    if (b >= 1)  { push(5); push(6); }
    push(7); push(8);
    if (b <= 30) { push(9); push(10); }
  }

  // ---- Q fragments: wave's 32 rows (two 16-row groups) ----
  const float* qb = q_ + ((size_t)nh * 4096 + (size_t)b * 128 + wid * 32) * 64;
  short8 qa[2][2];
#pragma unroll
  for (int mt = 0; mt < 2; ++mt)
#pragma unroll
    for (int kc = 0; kc < 2; ++kc) {
      const float* qp = qb + (size_t)(mt * 16 + c) * 64 + kc * 32 + g * 8;
      float4 f0 = *(const float4*)(qp);
      float4 f1 = *(const float4*)(qp + 4);
      short8 tq;
      tq[0] = f2bf(f0.x); tq[1] = f2bf(f0.y); tq[2] = f2bf(f0.z); tq[3] = f2bf(f0.w);
      tq[4] = f2bf(f1.x); tq[5] = f2bf(f1.y); tq[6] = f2bf(f1.z); tq[7] = f2bf(f1.w);
      qa[mt][kc] = tq;
    }

  f32x4 acc[2][4];
#pragma unroll
  for (int mt = 0; mt < 2; ++mt)
#pragma unroll
    for (int dd = 0; dd < 4; ++dd) acc[mt][dd] = f32x4{0.f, 0.f, 0.f, 0.f};
  float mrun0 = 0.f, mrun1 = 0.f, lrun0 = 0.f, lrun1 = 0.f;

  auto src_for = [&](int t, const short*& kp, const short*& vp,
                     const float*& mp, int& stride) {
    if (t == 0) {
      kp = KG + (size_t)nh * (64 * 64);
      vp = VTG + (size_t)nh * (64 * 64);
      mp = GM2 + n_ * 64;
      stride = 64;
    } else if (t <= 4) {
      int r0 = b * 32 + (t - 1) * 64 + (t >= 3 ? 96 : 0);
      kp = KS + ((size_t)nh * TPS + r0) * 64;
      vp = VTS + (size_t)nh * (64 * TPS) + r0;
      mp = SM2 + n_ * TPS + r0;
      stride = TPS;
    } else {
      int r0 = b * 128 + (t - 5) * 64;
      kp = KL + ((size_t)nh * TPL + r0) * 64;
      vp = VTL + (size_t)nh * (64 * TPL) + r0;
      mp = AM2 + n_ * TPL + r0;
      stride = TPL;
    }
  };

  short8 kr0, kr1, vr0, vr1;

  // ---- prologue: tile[0] -> buf0; tile[1] -> regs ----
  {
    const short* kp; const short* vp; const float* mp; int st;
    src_for(0, kp, vp, mp, st);
    kr0 = *(const short8*)(kp + skey0 * 64 + ch * 8);
    kr1 = *(const short8*)(kp + skey1 * 64 + ch * 8);
    vr0 = *(const short8*)(vp + (size_t)row0 * st + ch * 8);
    vr1 = *(const short8*)(vp + (size_t)row1 * st + ch * 8);
    *(short8*)(smem + stg0) = kr0;
    *(short8*)(smem + stg1) = kr1;
    *(short8*)(smem + 16384 + stg0) = vr0;
    *(short8*)(smem + 16384 + stg1) = vr1;
    src_for((int)((enc >> 4) & 15ull), kp, vp, mp, st);   // nt >= 7 always
    kr0 = *(const short8*)(kp + skey0 * 64 + ch * 8);
    kr1 = *(const short8*)(kp + skey1 * 64 + ch * 8);
    vr0 = *(const short8*)(vp + (size_t)row0 * st + ch * 8);
    vr1 = *(const short8*)(vp + (size_t)row1 * st + ch * 8);
  }

  for (int i = 0; i < nt; ++i) {
    // own LDS ops drained, then workgroup barrier; vmcnt NOT drained
    asm volatile("s_waitcnt lgkmcnt(0)\n\ts_barrier" ::: "memory");
    const int cur = i & 1, nxt = cur ^ 1;
    char* kbuf = smem + cur * 8192;
    char* vbuf = smem + 16384 + cur * 8192;

    // ---- current tile's mask fragments (MFMA C-operands) ----
    // lane (c,g) holds keys (kt>>1)*32 + g*8 + (kt&1)*4 + j
    f32x4 mk[4];
    {
      int tl = (int)((enc >> (4 * i)) & 15ull);
      const short* kp; const short* vp; const float* mp; int st;
      src_for(tl, kp, vp, mp, st);
#pragma unroll
      for (int kt = 0; kt < 4; ++kt)
        mk[kt] = *(const f32x4*)(mp + ((kt >> 1) << 5) + g * 8 + ((kt & 1) << 2));
    }

    // ---- QK^T swapped, per-kt bk lifetime; mask as C-in; scores -> p ----
    f32x4 p40[4], p41[4];
    __builtin_amdgcn_s_setprio(1);
#pragma unroll
    for (int kt = 0; kt < 4; ++kt) {
      unsigned off0 = ((unsigned)(kt * 16 + c) << 7) +
                      ((unsigned)(g * 16) ^ ((unsigned)(c & 7) << 4));
      unsigned off1 = ((unsigned)(kt * 16 + c) << 7) +
                      ((unsigned)(64 + g * 16) ^ ((unsigned)(c & 7) << 4));
      short8 bk0 = *(const short8*)(kbuf + off0);
      short8 bk1 = *(const short8*)(kbuf + off1);
      f32x4 z0 = __builtin_amdgcn_mfma_f32_16x16x32_bf16(bk0, qa[0][0], mk[kt], 0, 0, 0);
      z0 = __builtin_amdgcn_mfma_f32_16x16x32_bf16(bk1, qa[0][1], z0, 0, 0, 0);
      p40[kt] = z0;
      f32x4 z1 = __builtin_amdgcn_mfma_f32_16x16x32_bf16(bk0, qa[1][0], mk[kt], 0, 0, 0);
      z1 = __builtin_amdgcn_mfma_f32_16x16x32_bf16(bk1, qa[1][1], z1, 0, 0, 0);
      p41[kt] = z1;
    }
    __builtin_amdgcn_s_setprio(0);

    // ---- write staged tile[i+1]; prefetch tile[i+2] ----
    if (i + 1 < nt) {
      *(short8*)(smem + nxt * 8192 + stg0) = kr0;
      *(short8*)(smem + nxt * 8192 + stg1) = kr1;
      *(short8*)(smem + 16384 + nxt * 8192 + stg0) = vr0;
      *(short8*)(smem + 16384 + nxt * 8192 + stg1) = vr1;
    }
    if (i + 2 < nt) {
      int tn = (int)((enc >> (4 * (i + 2))) & 15ull);
      const short* kp; const short* vp; const float* mp; int st;
      src_for(tn, kp, vp, mp, st);
      kr0 = *(const short8*)(kp + skey0 * 64 + ch * 8);
      kr1 = *(const short8*)(kp + skey1 * 64 + ch * 8);
      vr0 = *(const short8*)(vp + (size_t)row0 * st + ch * 8);
      vr1 = *(const short8*)(vp + (size_t)row1 * st + ch * 8);
    }

    // ---- softmax: exp in place (optimistic), per-lane partial sums ----
    float rs0 = 0.f, rs1 = 0.f;
#pragma unroll
    for (int kt = 0; kt < 4; ++kt)
#pragma unroll
      for (int j = 0; j < 4; ++j) {
        float p0 = exp2g(p40[kt][j] - mrun0);
        float p1 = exp2g(p41[kt][j] - mrun1);
        p40[kt][j] = p0; rs0 += p0;
        p41[kt][j] = p1; rs1 += p1;
      }

    if (__any(fmaxf(rs0, rs1) > 1024.f)) {  // first tile + rare genuine growth
      // ---- mt = 0 (named arrays only; NO address-taken locals) ----
      {
        float tot = rs0;
        tot += __shfl_xor(tot, 16);
        tot += __shfl_xor(tot, 32);          // full row sum for query c
        float rsc = fmaxf(tot, 1.0f);
        float sc = 1.0f / rsc;
        mrun0 += log2g(rsc);
#pragma unroll
        for (int kt = 0; kt < 4; ++kt) p40[kt] *= sc;
        lrun0 = (lrun0 + rs0) * sc;
        if (lane < 16) sclw[lane] = sc;
      }
      // ---- mt = 1 ----
      {
        float tot = rs1;
        tot += __shfl_xor(tot, 16);
        tot += __shfl_xor(tot, 32);
        float rsc = fmaxf(tot, 1.0f);
        float sc = 1.0f / rsc;
        mrun1 += log2g(rsc);
#pragma unroll
        for (int kt = 0; kt < 4; ++kt) p41[kt] *= sc;
        lrun1 = (lrun1 + rs1) * sc;
        if (lane < 16) sclw[16 + lane] = sc;
      }
      // acc rescale needs per-query sc in D-layout (row = 4g+j)
      asm volatile("s_waitcnt lgkmcnt(0)" ::: "memory");
      f32x4 sq0 = *(const f32x4*)&sclw[4 * g];
      f32x4 sq1 = *(const f32x4*)&sclw[16 + 4 * g];
#pragma unroll
      for (int dd = 0; dd < 4; ++dd)
#pragma unroll
        for (int j = 0; j < 4; ++j) {
          acc[0][dd][j] *= sq0[j];
          acc[1][dd][j] *= sq1[j];
        }
    } else {
      lrun0 += rs0;
      lrun1 += rs1;
    }

    // ---- pack P (own regs) and PV: bv read once, feeds both mt ----
#pragma unroll
    for (int kk = 0; kk < 2; ++kk) {
      u32x4 u0, u1;
      u0[0] = cvt_pk_bf16(p40[2 * kk][0], p40[2 * kk][1]);
      u0[1] = cvt_pk_bf16(p40[2 * kk][2], p40[2 * kk][3]);
      u0[2] = cvt_pk_bf16(p40[2 * kk + 1][0], p40[2 * kk + 1][1]);
      u0[3] = cvt_pk_bf16(p40[2 * kk + 1][2], p40[2 * kk + 1][3]);
      u1[0] = cvt_pk_bf16(p41[2 * kk][0], p41[2 * kk][1]);
      u1[1] = cvt_pk_bf16(p41[2 * kk][2], p41[2 * kk][3]);
      u1[2] = cvt_pk_bf16(p41[2 * kk + 1][0], p41[2 * kk + 1][1]);
      u1[3] = cvt_pk_bf16(p41[2 * kk + 1][2], p41[2 * kk + 1][3]);
      short8 pa0 = __builtin_bit_cast(short8, u0);
      short8 pa1 = __builtin_bit_cast(short8, u1);
      __builtin_amdgcn_s_setprio(1);
#pragma unroll
      for (int dd = 0; dd < 4; ++dd) {
        unsigned voff = ((unsigned)(dd * 16 + c) << 7) +
                        ((unsigned)(kk * 64 + g * 16) ^ ((unsigned)(c & 7) << 4));
        short8 bv = *(const short8*)(vbuf + voff);
        acc[0][dd] = __builtin_amdgcn_mfma_f32_16x16x32_bf16(pa0, bv, acc[0][dd], 0, 0, 0);
        acc[1][dd] = __builtin_amdgcn_mfma_f32_16x16x32_bf16(pa1, bv, acc[1][dd], 0, 0, 0);
      }
      __builtin_amdgcn_s_setprio(0);
    }
  }

  // ---- epilogue: reduce l over key-groups, redistribute, store ----
  {
    float l0 = lrun0;
    l0 += __shfl_xor(l0, 16);
    l0 += __shfl_xor(l0, 32);
    float l1 = lrun1;
    l1 += __shfl_xor(l1, 16);
    l1 += __shfl_xor(l1, 32);
    if (lane < 16) {
      sclw[lane] = 1.f / l0;
      sclw[16 + lane] = 1.f / l1;
    }
  }
  __syncthreads();
  f32x4 iv0 = *(const f32x4*)&sclw[4 * g];
  f32x4 iv1 = *(const f32x4*)&sclw[16 + 4 * g];
  __syncthreads();   // iv read everywhere -> LDS reusable as fp32 staging
  float* fst = (float*)smem + wid * (32 * 68);   // per-wave [32][68] fp32
#pragma unroll
  for (int j = 0; j < 4; ++j)
#pragma unroll
    for (int dd = 0; dd < 4; ++dd) {
      fst[(4 * g + j) * 68 + dd * 16 + c] = acc[0][dd][j] * iv0[j];
      fst[(16 + 4 * g + j) * 68 + dd * 16 + c] = acc[1][dd][j] * iv1[j];
    }
  int rr = lane >> 1, hh = lane & 1;
  const float* fs = fst + rr * 68 + hh * 32;
  float* op = out + ((size_t)nh * 4096 + (size_t)b * 128 + wid * 32 + rr) * 64 + hh * 32;
#pragma unroll
  for (int i = 0; i < 8; ++i)
    *(float4*)(op + i * 4) = *(const float4*)(fs + i * 4);
}

// ---------------- fallback (round-1 kernel, used if ws too small) -----------
__global__ __launch_bounds__(256) void lsg_attn_fb(
    const float* __restrict__ q_,  const float* __restrict__ k_,
    const float* __restrict__ v_,  const float* __restrict__ amask,
    const float* __restrict__ sk,  const float* __restrict__ sv,
    const float* __restrict__ smk, const float* __restrict__ gk,
    const float* __restrict__ gv,  const float* __restrict__ gmk,
    float* __restrict__ out) {
  constexpr int T = 4096, D = 64, TS = 1024;
  constexpr float NEGF = -3.402823466e38f;
  __shared__ __align__(16) short k_lds[32][72];
  __shared__ __align__(16) short v_lds[64][40];
  __shared__ __align__(16) short p_lds[4][32][40];
  __shared__ float m_lds[32];
  const int bid = blockIdx.x;
  const int b = bid & 31, nh = bid >> 5, n_ = nh / 12;
  const int tid = threadIdx.x, wid = tid >> 6, lane = tid & 63;
  const int c = lane & 15, g = lane >> 4;
  const float* qb = q_ + ((size_t)nh * T + (size_t)b * 128) * D;
  const float* kb = k_ + (size_t)nh * T * D;
  const float* vb = v_ + (size_t)nh * T * D;
  const float* skb = sk + (size_t)nh * TS * D;
  const float* svb = sv + (size_t)nh * TS * D;
  const float* gkb = gk + (size_t)nh * 64 * D;
  const float* gvb = gv + (size_t)nh * 64 * D;
  const float* am = amask + (size_t)n_ * T;
  const float* sm = smk + (size_t)n_ * TS;
  const float* gm = gmk + (size_t)n_ * 64;
  short8 qa[2][2];
#pragma unroll
  for (int mt = 0; mt < 2; ++mt)
#pragma unroll
    for (int kc = 0; kc < 2; ++kc) {
      const float* qp = qb + (size_t)(wid * 32 + mt * 16 + c) * D + kc * 32 + g * 8;
      short8 t;
#pragma unroll
      for (int j = 0; j < 8; ++j) t[j] = f2bf(qp[j]);
      qa[mt][kc] = t;
    }
  f32x4 acc[2][4];
#pragma unroll
  for (int mt = 0; mt < 2; ++mt)
#pragma unroll
    for (int dd = 0; dd < 4; ++dd) acc[mt][dd] = f32x4{0.f, 0.f, 0.f, 0.f};
  float mrun[2][4], lrun[2][4];
#pragma unroll
  for (int mt = 0; mt < 2; ++mt)
#pragma unroll
    for (int j = 0; j < 4; ++j) { mrun[mt][j] = NEGF; lrun[mt][j] = 0.f; }
  const int key_local = tid >> 3;
  const int seg = tid & 7;
  const int d0 = seg * 8;
  for (int tile = 0; tile < 22; ++tile) {
    __syncthreads();
    {
      const int kk = tile * 32 + key_local;
      const float* ksrc; const float* vsrc; float mval; bool valid;
      if (kk < 64) {
        ksrc = gkb + kk * D; vsrc = gvb + kk * D; mval = gm[kk]; valid = true;
      } else if (kk < 320) {
        int s = b * 32 - 160 + (kk - 64) + ((kk >= 192) ? 96 : 0);
        valid = (s >= 0) && (s < TS);
        int sc2 = valid ? s : 0;
        ksrc = skb + sc2 * D; vsrc = svb + sc2 * D;
        mval = valid ? sm[sc2] : NEGF;
      } else {
        int tt = b * 128 - 128 + (kk - 320);
        valid = (tt >= 0) && (tt < T);
        int tc = valid ? tt : 0;
        ksrc = kb + tc * D; vsrc = vb + tc * D;
        mval = valid ? am[tc] : NEGF;
      }
      short8 k8; short v8[8];
      if (valid) {
#pragma unroll
        for (int j = 0; j < 8; ++j) { k8[j] = f2bf(ksrc[d0 + j]); v8[j] = f2bf(vsrc[d0 + j]); }
      } else {
#pragma unroll
        for (int j = 0; j < 8; ++j) { k8[j] = 0; v8[j] = 0; }
      }
      *(short8*)(&k_lds[key_local][d0]) = k8;
#pragma unroll
      for (int j = 0; j < 8; ++j) v_lds[d0 + j][key_local] = v8[j];
      if (seg == 0) m_lds[key_local] = mval;
    }
    __syncthreads();
    short8 bk[2][2];
#pragma unroll
    for (int kt = 0; kt < 2; ++kt)
#pragma unroll
      for (int kc = 0; kc < 2; ++kc)
        bk[kt][kc] = *(const short8*)(&k_lds[kt * 16 + c][kc * 32 + g * 8]);
    f32x4 s_[2][2];
#pragma unroll
    for (int mt = 0; mt < 2; ++mt)
#pragma unroll
      for (int kt = 0; kt < 2; ++kt) {
        f32x4 z = f32x4{0.f, 0.f, 0.f, 0.f};
        z = __builtin_amdgcn_mfma_f32_16x16x32_bf16(qa[mt][0], bk[kt][0], z, 0, 0, 0);
        z = __builtin_amdgcn_mfma_f32_16x16x32_bf16(qa[mt][1], bk[kt][1], z, 0, 0, 0);
        s_[mt][kt] = z;
      }
    const float msk0 = m_lds[c];
    const float msk1 = m_lds[16 + c];
#pragma unroll
    for (int mt = 0; mt < 2; ++mt) {
#pragma unroll
      for (int j = 0; j < 4; ++j) {
        float s0 = s_[mt][0][j] * 0.125f + msk0;
        float s1 = s_[mt][1][j] * 0.125f + msk1;
        float tv = fmaxf(s0, s1);
        tv = fmaxf(tv, __shfl_xor(tv, 1));
        tv = fmaxf(tv, __shfl_xor(tv, 2));
        tv = fmaxf(tv, __shfl_xor(tv, 4));
        tv = fmaxf(tv, __shfl_xor(tv, 8));
        float mold = mrun[mt][j];
        float mnew = fmaxf(mold, tv);
        float scale = __expf(mold - mnew);
        mrun[mt][j] = mnew;
        float p0 = __expf(s0 - mnew);
        float p1 = __expf(s1 - mnew);
        lrun[mt][j] = lrun[mt][j] * scale + p0 + p1;
#pragma unroll
        for (int dd = 0; dd < 4; ++dd) acc[mt][dd][j] *= scale;
        p_lds[wid][mt * 16 + g * 4 + j][c] = f2bf(p0);
        p_lds[wid][mt * 16 + g * 4 + j][16 + c] = f2bf(p1);
      }
    }
    __syncthreads();
#pragma unroll
    for (int mt = 0; mt < 2; ++mt) {
      short8 pa = *(const short8*)(&p_lds[wid][mt * 16 + c][g * 8]);
#pragma unroll
      for (int dd = 0; dd < 4; ++dd) {
        short8 bv = *(const short8*)(&v_lds[dd * 16 + c][g * 8]);
        acc[mt][dd] = __builtin_amdgcn_mfma_f32_16x16x32_bf16(pa, bv, acc[mt][dd], 0, 0, 0);
      }
    }
  }
  float* ob = out + ((size_t)nh * T + (size_t)b * 128 + (size_t)wid * 32) * D;
#pragma unroll
  for (int mt = 0; mt < 2; ++mt)
#pragma unroll
    for (int j = 0; j < 4; ++j) {
      float l = lrun[mt][j];
      l += __shfl_xor(l, 1);
      l += __shfl_xor(l, 2);
      l += __shfl_xor(l, 4);
      l += __shfl_xor(l, 8);
      float inv = 1.f / l;
      int row = mt * 16 + g * 4 + j;
#pragma unroll
      for (int dd = 0; dd < 4; ++dd)
        ob[(size_t)row * D + dd * 16 + c] = acc[mt][dd][j] * inv;
    }
}

extern "C" void kernel_launch(void* const* d_in, const int* in_sizes, int n_in,
                              void* d_out, int out_size, void* d_ws, size_t ws_size,
                              hipStream_t stream) {
  const float* q  = (const float*)d_in[0];
  const float* k  = (const float*)d_in[1];
  const float* v  = (const float*)d_in[2];
  const float* am = (const float*)d_in[3];
  const float* sk = (const float*)d_in[4];
  const float* sv = (const float*)d_in[5];
  const float* sm = (const float*)d_in[6];
  const float* gk = (const float*)d_in[7];
  const float* gv = (const float*)d_in[8];
  const float* gm = (const float*)d_in[9];
  float* out = (float*)d_out;

  size_t off = 0;
  char* base = (char*)d_ws;
  auto alloc = [&](size_t bytes) { void* p = base + off; off += bytes; return p; };
  short* KL  = (short*)alloc(13369344);  // [24][4352][64] bf16 (pre-scaled)
  short* VTL = (short*)alloc(13369344);  // [24][64][4352]
  short* KS  = (short*)alloc(4128768);   // [24][1344][64]
  short* VTS = (short*)alloc(4128768);   // [24][64][1344]
  short* KG  = (short*)alloc(196608);    // [24][64][64]
  short* VTG = (short*)alloc(196608);    // [24][64][64]
  float* AM2 = (float*)alloc(34816);     // [2][4352]
  float* SM2 = (float*)alloc(10752);     // [2][1344]
  float* GM2 = (float*)alloc(512);       // [2][64]

  if (off <= ws_size) {
    hipLaunchKernelGGL(prepass_all, dim3(6525), dim3(256), 0, stream,
                       k, sk, gk, v, sv, gv, KL, KS, KG, VTL, VTS, VTG,
                       am, sm, gm, AM2, SM2, GM2);
    hipLaunchKernelGGL(lsg_attn12, dim3(768), dim3(256), 0, stream,
                       KL, VTL, KS, VTS, KG, VTG, AM2, SM2, GM2, q, out);
  } else {
    hipLaunchKernelGGL(lsg_attn_fb, dim3(768), dim3(256), 0, stream,
                       q, k, v, am, sk, sv, sm, gk, gv, gm, out);
  }
}

// Round 15
// 53.531 us; speedup vs baseline: 1.5693x; 1.3855x over previous
//
#include <hip/hip_runtime.h>
#include <hip/hip_bf16.h>

typedef __attribute__((ext_vector_type(8))) short short8;
typedef __attribute__((ext_vector_type(4))) float f32x4;
typedef __attribute__((ext_vector_type(4))) unsigned u32x4;

#define LOG2E 1.44269504f
#define SCL2  0.18033688f   // 0.125 * log2(e)
#define MNEG  -3.0e38f

__device__ __forceinline__ short f2bf(float f) {
  union { float f; unsigned u; } x; x.f = f;
  return (short)((x.u + 0x7FFFu + ((x.u >> 16) & 1u)) >> 16);  // RNE
}
__device__ __forceinline__ float exp2g(float x) {
  float r; asm("v_exp_f32 %0, %1" : "=v"(r) : "v"(x)); return r;
}
__device__ __forceinline__ float log2g(float x) {
  float r; asm("v_log_f32 %0, %1" : "=v"(r) : "v"(x)); return r;
}
__device__ __forceinline__ unsigned cvt_pk_bf16(float lo, float hi) {
  unsigned r;
  asm("v_cvt_pk_bf16_f32 %0, %1, %2" : "=v"(r) : "v"(lo), "v"(hi));
  return r;
}

// ---------------- fused prepass: K conv x3 (pre-scaled by SCL2) | V^T | masks
__device__ __forceinline__ void conv_one(
    const float* __restrict__ src, short* __restrict__ dst,
    int Tin, int pad, int cid) {
  int Tpad = Tin + 2 * pad;
  int row = cid >> 3;
  int d0 = (cid & 7) * 8;
  int tok = row % Tpad;
  int nh = row / Tpad;
  int st = tok - pad;
  short8 o;
  if (st >= 0 && st < Tin) {
    const float4* sp = (const float4*)(src + ((size_t)nh * Tin + st) * 64 + d0);
    float4 f0 = sp[0], f1 = sp[1];
    o[0] = f2bf(f0.x * SCL2); o[1] = f2bf(f0.y * SCL2);
    o[2] = f2bf(f0.z * SCL2); o[3] = f2bf(f0.w * SCL2);
    o[4] = f2bf(f1.x * SCL2); o[5] = f2bf(f1.y * SCL2);
    o[6] = f2bf(f1.z * SCL2); o[7] = f2bf(f1.w * SCL2);
  } else {
#pragma unroll
    for (int j = 0; j < 8; ++j) o[j] = 0;
  }
  *(short8*)(dst + (size_t)row * 64 + d0) = o;
}

__device__ __forceinline__ void transv_one(
    const float* __restrict__ src, short* __restrict__ dst,
    int Tin, int pad, int tiles, int bidx, int tid, short (*lt)[72]) {
  int tile = bidx % tiles;
  int nh = bidx / tiles;
  int Tpad = Tin + 2 * pad;
  int c0 = tile * 64;
  int tok = tid >> 2;
  int dc = (tid & 3) * 16;
  int st = c0 + tok - pad;
  if (st >= 0 && st < Tin) {
    const float4* sp = (const float4*)(src + ((size_t)nh * Tin + st) * 64 + dc);
#pragma unroll
    for (int i = 0; i < 4; ++i) {
      float4 f = sp[i];
      lt[tok][dc + i * 4 + 0] = f2bf(f.x);
      lt[tok][dc + i * 4 + 1] = f2bf(f.y);
      lt[tok][dc + i * 4 + 2] = f2bf(f.z);
      lt[tok][dc + i * 4 + 3] = f2bf(f.w);
    }
  } else {
#pragma unroll
    for (int i = 0; i < 16; ++i) lt[tok][dc + i] = 0;
  }
  __syncthreads();
  int d = tid >> 2;
  int tc = (tid & 3) * 16;
  short8 o0, o1;
#pragma unroll
  for (int j = 0; j < 8; ++j) { o0[j] = lt[tc + j][d]; o1[j] = lt[tc + 8 + j][d]; }
  short* dp = dst + ((size_t)nh * 64 + d) * Tpad + c0 + tc;
  *(short8*)(dp) = o0;
  *(short8*)(dp + 8) = o1;
}

// block ranges: [0,3264) KL | +1008 KS | +48 KG | +1632 VTL | +504 VTS |
//               +24 VTG | +45 masks  => grid 6525
__global__ __launch_bounds__(256) void prepass_all(
    const float* __restrict__ K, const float* __restrict__ SK,
    const float* __restrict__ GK,
    const float* __restrict__ V, const float* __restrict__ SV,
    const float* __restrict__ GV,
    short* __restrict__ KL, short* __restrict__ KS, short* __restrict__ KG,
    short* __restrict__ VTL, short* __restrict__ VTS, short* __restrict__ VTG,
    const float* __restrict__ am, const float* __restrict__ sm,
    const float* __restrict__ gm,
    float* __restrict__ AM2, float* __restrict__ SM2, float* __restrict__ GM2) {
  __shared__ short lt[64][72];
  int bidx = blockIdx.x;
  int tid = threadIdx.x;
  if (bidx < 3264) { conv_one(K,  KL, 4096, 128, bidx * 256 + tid); return; }
  bidx -= 3264;
  if (bidx < 1008) { conv_one(SK, KS, 1024, 160, bidx * 256 + tid); return; }
  bidx -= 1008;
  if (bidx < 48)   { conv_one(GK, KG, 64, 0, bidx * 256 + tid); return; }
  bidx -= 48;
  if (bidx < 1632) { transv_one(V,  VTL, 4096, 128, 68, bidx, tid, lt); return; }
  bidx -= 1632;
  if (bidx < 504)  { transv_one(SV, VTS, 1024, 160, 21, bidx, tid, lt); return; }
  bidx -= 504;
  if (bidx < 24)   { transv_one(GV, VTG, 64, 0, 1, bidx, tid, lt); return; }
  bidx -= 24;
  int i = bidx * 256 + tid;   // mask work: 11520 elements exactly
  if (i < 2 * 4352) {
    int n = i / 4352, rr = i % 4352, s = rr - 128;
    AM2[i] = (s >= 0 && s < 4096) ? am[n * 4096 + s] * LOG2E : MNEG;
  } else if (i < 2 * 4352 + 2 * 1344) {
    int j = i - 2 * 4352;
    int n = j / 1344, rr = j % 1344, s = rr - 160;
    SM2[j] = (s >= 0 && s < 1024) ? sm[n * 1024 + s] * LOG2E : MNEG;
  } else {
    int j = i - 2 * 4352 - 2 * 1344;
    GM2[j] = gm[j] * LOG2E;
  }
}

#define MFMA_BF16 __builtin_amdgcn_mfma_f32_16x16x32_bf16

#define EXP4(Z, MR, RS)                         \
  Z[0] = exp2g(Z[0] - MR); RS += Z[0];          \
  Z[1] = exp2g(Z[1] - MR); RS += Z[1];          \
  Z[2] = exp2g(Z[2] - MR); RS += Z[2];          \
  Z[3] = exp2g(Z[3] - MR); RS += Z[3];

#define PACK(PA, ZL, ZH) {                                        \
  u32x4 uu_;                                                      \
  uu_[0] = cvt_pk_bf16(ZL[0], ZL[1]);                             \
  uu_[1] = cvt_pk_bf16(ZL[2], ZL[3]);                             \
  uu_[2] = cvt_pk_bf16(ZH[0], ZH[1]);                             \
  uu_[3] = cvt_pk_bf16(ZH[2], ZH[3]);                             \
  PA = __builtin_bit_cast(short8, uu_); }

#define PVALL(PA0, PA1, VRD) {                                    \
  short8 bv_;                                                     \
  bv_ = *(const short8*)(vbuf + (VRD));                           \
  acc00 = MFMA_BF16(PA0, bv_, acc00, 0, 0, 0);                    \
  acc10 = MFMA_BF16(PA1, bv_, acc10, 0, 0, 0);                    \
  bv_ = *(const short8*)(vbuf + 2048 + (VRD));                    \
  acc01 = MFMA_BF16(PA0, bv_, acc01, 0, 0, 0);                    \
  acc11 = MFMA_BF16(PA1, bv_, acc11, 0, 0, 0);                    \
  bv_ = *(const short8*)(vbuf + 4096 + (VRD));                    \
  acc02 = MFMA_BF16(PA0, bv_, acc02, 0, 0, 0);                    \
  acc12 = MFMA_BF16(PA1, bv_, acc12, 0, 0, 0);                    \
  bv_ = *(const short8*)(vbuf + 6144 + (VRD));                    \
  acc03 = MFMA_BF16(PA0, bv_, acc03, 0, 0, 0);                    \
  acc13 = MFMA_BF16(PA1, bv_, acc13, 0, 0, 0); }

// ---------------- main attention kernel (4 waves x 32q, streaming P) --------
// Per kt: QK^T (mask = MFMA C-in) -> exp2 in place -> cvt_pk pack -> PV.
// Scores/P live only transiently in 4 named f32x4 -> no local arrays to
// demote (rounds 12-14's scratch bug). Rare rescale applied POST-PV:
// (acc+PV)*sc == acc*sc + (P*sc)V, lrun=(lrun+rs)*sc, mrun+=log2(rsc).
// K staged bit-permuted so each lane's P values are its own PV A-fragment.
// K/V LDS: [64 rows][128 B], byte = row*128 + (col16 ^ ((row&7)<<4)).
// bv/bk reads feed 2x MFMA (two 16-row query groups) -> per-CU LDS traffic
// ~half of the 8-wave round-11 kernel (its bottleneck: LDS pipe ~48% busy).
__global__ __launch_bounds__(256, 3) void lsg_attn13(
    const short* __restrict__ KL, const short* __restrict__ VTL,
    const short* __restrict__ KS, const short* __restrict__ VTS,
    const short* __restrict__ KG, const short* __restrict__ VTG,
    const float* __restrict__ AM2, const float* __restrict__ SM2,
    const float* __restrict__ GM2,
    const float* __restrict__ q_, float* __restrict__ out) {
  constexpr int TPL = 4352, TPS = 1344;
  __shared__ __align__(16) char smem[35328];  // K dbuf 16K | V dbuf 16K | scl 512B

  int bid = blockIdx.x;
  bid = (bid & 7) * 96 + (bid >> 3);        // XCD-contiguous logical ids
  const int b = bid & 31, nh = bid >> 5, n_ = nh / 12;
  const int tid = threadIdx.x;
  const int wid = tid >> 6, lane = tid & 63;
  const int c = lane & 15, g = lane >> 4;
  // staging: wave writes rows [wid*8, +8) and [32+wid*8, +8), 8 chunks each
  const int rl = lane >> 3, ch = lane & 7;
  const int row0 = wid * 8 + rl, row1 = row0 + 32;
  auto perm = [](int r) {   // [kt1][g1 g0][kt0][j1 j0]
    return ((r >> 5) << 5) | (((r >> 2) & 3) << 3) |
           (((r >> 4) & 1) << 2) | (r & 3);
  };
  const int skey0 = perm(row0), skey1 = perm(row1);
  float* sclw = (float*)(smem + 32768) + wid * 32;
  const unsigned stg0 = ((unsigned)row0 << 7) +
                        ((unsigned)(ch * 16) ^ ((unsigned)(row0 & 7) << 4));
  const unsigned stg1 = ((unsigned)row1 << 7) +
                        ((unsigned)(ch * 16) ^ ((unsigned)(row1 & 7) << 4));
  const unsigned xsw = (unsigned)((c & 7) << 4);
  const unsigned rd0 = ((unsigned)c << 7) + (((unsigned)(g * 16)) ^ xsw);
  const unsigned rd1 = ((unsigned)c << 7) + (((unsigned)(64 + g * 16)) ^ xsw);

  // ---- tile list: live tiles only, 4 bits per entry ----
  unsigned long long enc = 0; int nt = 0;
  {
    auto push = [&](int t) { enc |= (unsigned long long)t << (4 * nt); ++nt; };
    push(0);
    if (b >= 4)  push(1);
    if (b >= 2)  push(2);
    if (b <= 29) push(3);
    if (b <= 27) push(4);
    if (b >= 1)  { push(5); push(6); }
    push(7); push(8);
    if (b <= 30) { push(9); push(10); }
  }

  // ---- Q fragments: wave's 32 rows, four named short8 ----
  const float* qb = q_ + ((size_t)nh * 4096 + (size_t)b * 128 + wid * 32) * 64;
  auto ldq = [&](int mt, int kc) {
    const float* qp = qb + (size_t)(mt * 16 + c) * 64 + kc * 32 + g * 8;
    float4 f0 = *(const float4*)(qp);
    float4 f1 = *(const float4*)(qp + 4);
    short8 t;
    t[0] = f2bf(f0.x); t[1] = f2bf(f0.y); t[2] = f2bf(f0.z); t[3] = f2bf(f0.w);
    t[4] = f2bf(f1.x); t[5] = f2bf(f1.y); t[6] = f2bf(f1.z); t[7] = f2bf(f1.w);
    return t;
  };
  short8 qa00 = ldq(0, 0), qa01 = ldq(0, 1);
  short8 qa10 = ldq(1, 0), qa11 = ldq(1, 1);

  const f32x4 zz = {0.f, 0.f, 0.f, 0.f};
  f32x4 acc00 = zz, acc01 = zz, acc02 = zz, acc03 = zz;
  f32x4 acc10 = zz, acc11 = zz, acc12 = zz, acc13 = zz;
  float mrun0 = 0.f, mrun1 = 0.f, lrun0 = 0.f, lrun1 = 0.f;

  auto src_for = [&](int t, const short*& kp, const short*& vp,
                     const float*& mp, int& stride) {
    if (t == 0) {
      kp = KG + (size_t)nh * (64 * 64);
      vp = VTG + (size_t)nh * (64 * 64);
      mp = GM2 + n_ * 64;
      stride = 64;
    } else if (t <= 4) {
      int r0 = b * 32 + (t - 1) * 64 + (t >= 3 ? 96 : 0);
      kp = KS + ((size_t)nh * TPS + r0) * 64;
      vp = VTS + (size_t)nh * (64 * TPS) + r0;
      mp = SM2 + n_ * TPS + r0;
      stride = TPS;
    } else {
      int r0 = b * 128 + (t - 5) * 64;
      kp = KL + ((size_t)nh * TPL + r0) * 64;
      vp = VTL + (size_t)nh * (64 * TPL) + r0;
      mp = AM2 + n_ * TPL + r0;
      stride = TPL;
    }
  };

  short8 kr0, kr1, vr0, vr1;

  // ---- prologue: tile[0] -> buf0; tile[1] -> regs ----
  {
    const short* kp; const short* vp; const float* mp; int st;
    src_for(0, kp, vp, mp, st);
    kr0 = *(const short8*)(kp + skey0 * 64 + ch * 8);
    kr1 = *(const short8*)(kp + skey1 * 64 + ch * 8);
    vr0 = *(const short8*)(vp + (size_t)row0 * st + ch * 8);
    vr1 = *(const short8*)(vp + (size_t)row1 * st + ch * 8);
    *(short8*)(smem + stg0) = kr0;
    *(short8*)(smem + stg1) = kr1;
    *(short8*)(smem + 16384 + stg0) = vr0;
    *(short8*)(smem + 16384 + stg1) = vr1;
    src_for((int)((enc >> 4) & 15ull), kp, vp, mp, st);   // nt >= 7 always
    kr0 = *(const short8*)(kp + skey0 * 64 + ch * 8);
    kr1 = *(const short8*)(kp + skey1 * 64 + ch * 8);
    vr0 = *(const short8*)(vp + (size_t)row0 * st + ch * 8);
    vr1 = *(const short8*)(vp + (size_t)row1 * st + ch * 8);
  }

  for (int i = 0; i < nt; ++i) {
    // own LDS ops drained, then workgroup barrier; vmcnt NOT drained
    asm volatile("s_waitcnt lgkmcnt(0)\n\ts_barrier" ::: "memory");
    const int cur = i & 1, nxt = cur ^ 1;
    char* kbuf = smem + cur * 8192;
    char* vbuf = smem + 16384 + cur * 8192;

    // ---- current tile's mask fragments (MFMA C-operands), named ----
    // lane (c,g) holds keys (kt>>1)*32 + g*8 + (kt&1)*4 + j
    f32x4 mk0, mk1, mk2, mk3;
    {
      int tl = (int)((enc >> (4 * i)) & 15ull);
      const short* kp; const short* vp; const float* mp; int st;
      src_for(tl, kp, vp, mp, st);
      const float* mg = mp + g * 8;
      mk0 = *(const f32x4*)(mg);
      mk1 = *(const f32x4*)(mg + 4);
      mk2 = *(const f32x4*)(mg + 32);
      mk3 = *(const f32x4*)(mg + 36);
    }

    float rs0 = 0.f, rs1 = 0.f;

    // ===== kk = 0: kt 0,1 -> QK^T -> exp -> pack -> PV =====
    {
      __builtin_amdgcn_s_setprio(1);
      short8 bk0 = *(const short8*)(kbuf + rd0);
      short8 bk1 = *(const short8*)(kbuf + rd1);
      f32x4 zA0 = MFMA_BF16(bk0, qa00, mk0, 0, 0, 0);
      zA0 = MFMA_BF16(bk1, qa01, zA0, 0, 0, 0);
      f32x4 zA1 = MFMA_BF16(bk0, qa10, mk0, 0, 0, 0);
      zA1 = MFMA_BF16(bk1, qa11, zA1, 0, 0, 0);
      bk0 = *(const short8*)(kbuf + 2048 + rd0);
      bk1 = *(const short8*)(kbuf + 2048 + rd1);
      f32x4 zB0 = MFMA_BF16(bk0, qa00, mk1, 0, 0, 0);
      zB0 = MFMA_BF16(bk1, qa01, zB0, 0, 0, 0);
      f32x4 zB1 = MFMA_BF16(bk0, qa10, mk1, 0, 0, 0);
      zB1 = MFMA_BF16(bk1, qa11, zB1, 0, 0, 0);
      __builtin_amdgcn_s_setprio(0);
      EXP4(zA0, mrun0, rs0)
      EXP4(zB0, mrun0, rs0)
      EXP4(zA1, mrun1, rs1)
      EXP4(zB1, mrun1, rs1)
      short8 pa0, pa1;
      PACK(pa0, zA0, zB0)
      PACK(pa1, zA1, zB1)
      __builtin_amdgcn_s_setprio(1);
      PVALL(pa0, pa1, rd0)
      __builtin_amdgcn_s_setprio(0);
    }

    // ---- write staged tile[i+1]; prefetch tile[i+2] (overlap) ----
    if (i + 1 < nt) {
      *(short8*)(smem + nxt * 8192 + stg0) = kr0;
      *(short8*)(smem + nxt * 8192 + stg1) = kr1;
      *(short8*)(smem + 16384 + nxt * 8192 + stg0) = vr0;
      *(short8*)(smem + 16384 + nxt * 8192 + stg1) = vr1;
    }
    if (i + 2 < nt) {
      int tn = (int)((enc >> (4 * (i + 2))) & 15ull);
      const short* kp; const short* vp; const float* mp; int st;
      src_for(tn, kp, vp, mp, st);
      kr0 = *(const short8*)(kp + skey0 * 64 + ch * 8);
      kr1 = *(const short8*)(kp + skey1 * 64 + ch * 8);
      vr0 = *(const short8*)(vp + (size_t)row0 * st + ch * 8);
      vr1 = *(const short8*)(vp + (size_t)row1 * st + ch * 8);
    }

    // ===== kk = 1: kt 2,3 =====
    {
      __builtin_amdgcn_s_setprio(1);
      short8 bk0 = *(const short8*)(kbuf + 4096 + rd0);
      short8 bk1 = *(const short8*)(kbuf + 4096 + rd1);
      f32x4 zA0 = MFMA_BF16(bk0, qa00, mk2, 0, 0, 0);
      zA0 = MFMA_BF16(bk1, qa01, zA0, 0, 0, 0);
      f32x4 zA1 = MFMA_BF16(bk0, qa10, mk2, 0, 0, 0);
      zA1 = MFMA_BF16(bk1, qa11, zA1, 0, 0, 0);
      bk0 = *(const short8*)(kbuf + 6144 + rd0);
      bk1 = *(const short8*)(kbuf + 6144 + rd1);
      f32x4 zB0 = MFMA_BF16(bk0, qa00, mk3, 0, 0, 0);
      zB0 = MFMA_BF16(bk1, qa01, zB0, 0, 0, 0);
      f32x4 zB1 = MFMA_BF16(bk0, qa10, mk3, 0, 0, 0);
      zB1 = MFMA_BF16(bk1, qa11, zB1, 0, 0, 0);
      __builtin_amdgcn_s_setprio(0);
      EXP4(zA0, mrun0, rs0)
      EXP4(zB0, mrun0, rs0)
      EXP4(zA1, mrun1, rs1)
      EXP4(zB1, mrun1, rs1)
      short8 pa0, pa1;
      PACK(pa0, zA0, zB0)
      PACK(pa1, zA1, zB1)
      __builtin_amdgcn_s_setprio(1);
      PVALL(pa0, pa1, rd1)
      __builtin_amdgcn_s_setprio(0);
    }

    // ---- rare rescale, applied POST-PV (scales old acc + this tile) ----
    if (__any(fmaxf(rs0, rs1) > 1024.f)) {
      {
        float tot = rs0;
        tot += __shfl_xor(tot, 16);
        tot += __shfl_xor(tot, 32);          // full row sum for query c
        float rsc = fmaxf(tot, 1.0f);
        float sc = 1.0f / rsc;
        mrun0 += log2g(rsc);
        lrun0 = (lrun0 + rs0) * sc;
        if (lane < 16) sclw[lane] = sc;
      }
      {
        float tot = rs1;
        tot += __shfl_xor(tot, 16);
        tot += __shfl_xor(tot, 32);
        float rsc = fmaxf(tot, 1.0f);
        float sc = 1.0f / rsc;
        mrun1 += log2g(rsc);
        lrun1 = (lrun1 + rs1) * sc;
        if (lane < 16) sclw[16 + lane] = sc;
      }
      // acc rescale needs per-query sc in D-layout (row = 4g+j)
      f32x4 sq0 = *(const f32x4*)&sclw[4 * g];
      f32x4 sq1 = *(const f32x4*)&sclw[16 + 4 * g];
      acc00 *= sq0; acc01 *= sq0; acc02 *= sq0; acc03 *= sq0;
      acc10 *= sq1; acc11 *= sq1; acc12 *= sq1; acc13 *= sq1;
    } else {
      lrun0 += rs0;
      lrun1 += rs1;
    }
  }

  // ---- epilogue: reduce l over key-groups, redistribute, store ----
  {
    float l0 = lrun0;
    l0 += __shfl_xor(l0, 16);
    l0 += __shfl_xor(l0, 32);
    float l1 = lrun1;
    l1 += __shfl_xor(l1, 16);
    l1 += __shfl_xor(l1, 32);
    if (lane < 16) {
      sclw[lane] = 1.f / l0;
      sclw[16 + lane] = 1.f / l1;
    }
  }
  __syncthreads();
  f32x4 iv0 = *(const f32x4*)&sclw[4 * g];
  f32x4 iv1 = *(const f32x4*)&sclw[16 + 4 * g];
  __syncthreads();   // iv read everywhere -> LDS reusable as fp32 staging
  float* fst = (float*)smem + wid * (32 * 68);   // per-wave [32][68] fp32
#pragma unroll
  for (int j = 0; j < 4; ++j) {
    float* fr0 = fst + (4 * g + j) * 68 + c;
    fr0[0]  = acc00[j] * iv0[j];
    fr0[16] = acc01[j] * iv0[j];
    fr0[32] = acc02[j] * iv0[j];
    fr0[48] = acc03[j] * iv0[j];
    float* fr1 = fst + (16 + 4 * g + j) * 68 + c;
    fr1[0]  = acc10[j] * iv1[j];
    fr1[16] = acc11[j] * iv1[j];
    fr1[32] = acc12[j] * iv1[j];
    fr1[48] = acc13[j] * iv1[j];
  }
  int rr = lane >> 1, hh = lane & 1;
  const float* fs = fst + rr * 68 + hh * 32;
  float* op = out + ((size_t)nh * 4096 + (size_t)b * 128 + wid * 32 + rr) * 64 + hh * 32;
#pragma unroll
  for (int i = 0; i < 8; ++i)
    *(float4*)(op + i * 4) = *(const float4*)(fs + i * 4);
}

// ---------------- fallback (round-1 kernel, used if ws too small) -----------
__global__ __launch_bounds__(256) void lsg_attn_fb(
    const float* __restrict__ q_,  const float* __restrict__ k_,
    const float* __restrict__ v_,  const float* __restrict__ amask,
    const float* __restrict__ sk,  const float* __restrict__ sv,
    const float* __restrict__ smk, const float* __restrict__ gk,
    const float* __restrict__ gv,  const float* __restrict__ gmk,
    float* __restrict__ out) {
  constexpr int T = 4096, D = 64, TS = 1024;
  constexpr float NEGF = -3.402823466e38f;
  __shared__ __align__(16) short k_lds[32][72];
  __shared__ __align__(16) short v_lds[64][40];
  __shared__ __align__(16) short p_lds[4][32][40];
  __shared__ float m_lds[32];
  const int bid = blockIdx.x;
  const int b = bid & 31, nh = bid >> 5, n_ = nh / 12;
  const int tid = threadIdx.x, wid = tid >> 6, lane = tid & 63;
  const int c = lane & 15, g = lane >> 4;
  const float* qb = q_ + ((size_t)nh * T + (size_t)b * 128) * D;
  const float* kb = k_ + (size_t)nh * T * D;
  const float* vb = v_ + (size_t)nh * T * D;
  const float* skb = sk + (size_t)nh * TS * D;
  const float* svb = sv + (size_t)nh * TS * D;
  const float* gkb = gk + (size_t)nh * 64 * D;
  const float* gvb = gv + (size_t)nh * 64 * D;
  const float* am = amask + (size_t)n_ * T;
  const float* sm = smk + (size_t)n_ * TS;
  const float* gm = gmk + (size_t)n_ * 64;
  short8 qa[2][2];
#pragma unroll
  for (int mt = 0; mt < 2; ++mt)
#pragma unroll
    for (int kc = 0; kc < 2; ++kc) {
      const float* qp = qb + (size_t)(wid * 32 + mt * 16 + c) * D + kc * 32 + g * 8;
      short8 t;
#pragma unroll
      for (int j = 0; j < 8; ++j) t[j] = f2bf(qp[j]);
      qa[mt][kc] = t;
    }
  f32x4 acc[2][4];
#pragma unroll
  for (int mt = 0; mt < 2; ++mt)
#pragma unroll
    for (int dd = 0; dd < 4; ++dd) acc[mt][dd] = f32x4{0.f, 0.f, 0.f, 0.f};
  float mrun[2][4], lrun[2][4];
#pragma unroll
  for (int mt = 0; mt < 2; ++mt)
#pragma unroll
    for (int j = 0; j < 4; ++j) { mrun[mt][j] = NEGF; lrun[mt][j] = 0.f; }
  const int key_local = tid >> 3;
  const int seg = tid & 7;
  const int d0 = seg * 8;
  for (int tile = 0; tile < 22; ++tile) {
    __syncthreads();
    {
      const int kk = tile * 32 + key_local;
      const float* ksrc; const float* vsrc; float mval; bool valid;
      if (kk < 64) {
        ksrc = gkb + kk * D; vsrc = gvb + kk * D; mval = gm[kk]; valid = true;
      } else if (kk < 320) {
        int s = b * 32 - 160 + (kk - 64) + ((kk >= 192) ? 96 : 0);
        valid = (s >= 0) && (s < TS);
        int sc2 = valid ? s : 0;
        ksrc = skb + sc2 * D; vsrc = svb + sc2 * D;
        mval = valid ? sm[sc2] : NEGF;
      } else {
        int tt = b * 128 - 128 + (kk - 320);
        valid = (tt >= 0) && (tt < T);
        int tc = valid ? tt : 0;
        ksrc = kb + tc * D; vsrc = vb + tc * D;
        mval = valid ? am[tc] : NEGF;
      }
      short8 k8; short v8[8];
      if (valid) {
#pragma unroll
        for (int j = 0; j < 8; ++j) { k8[j] = f2bf(ksrc[d0 + j]); v8[j] = f2bf(vsrc[d0 + j]); }
      } else {
#pragma unroll
        for (int j = 0; j < 8; ++j) { k8[j] = 0; v8[j] = 0; }
      }
      *(short8*)(&k_lds[key_local][d0]) = k8;
#pragma unroll
      for (int j = 0; j < 8; ++j) v_lds[d0 + j][key_local] = v8[j];
      if (seg == 0) m_lds[key_local] = mval;
    }
    __syncthreads();
    short8 bk[2][2];
#pragma unroll
    for (int kt = 0; kt < 2; ++kt)
#pragma unroll
      for (int kc = 0; kc < 2; ++kc)
        bk[kt][kc] = *(const short8*)(&k_lds[kt * 16 + c][kc * 32 + g * 8]);
    f32x4 s_[2][2];
#pragma unroll
    for (int mt = 0; mt < 2; ++mt)
#pragma unroll
      for (int kt = 0; kt < 2; ++kt) {
        f32x4 z = f32x4{0.f, 0.f, 0.f, 0.f};
        z = __builtin_amdgcn_mfma_f32_16x16x32_bf16(qa[mt][0], bk[kt][0], z, 0, 0, 0);
        z = __builtin_amdgcn_mfma_f32_16x16x32_bf16(qa[mt][1], bk[kt][1], z, 0, 0, 0);
        s_[mt][kt] = z;
      }
    const float msk0 = m_lds[c];
    const float msk1 = m_lds[16 + c];
#pragma unroll
    for (int mt = 0; mt < 2; ++mt) {
#pragma unroll
      for (int j = 0; j < 4; ++j) {
        float s0 = s_[mt][0][j] * 0.125f + msk0;
        float s1 = s_[mt][1][j] * 0.125f + msk1;
        float tv = fmaxf(s0, s1);
        tv = fmaxf(tv, __shfl_xor(tv, 1));
        tv = fmaxf(tv, __shfl_xor(tv, 2));
        tv = fmaxf(tv, __shfl_xor(tv, 4));
        tv = fmaxf(tv, __shfl_xor(tv, 8));
        float mold = mrun[mt][j];
        float mnew = fmaxf(mold, tv);
        float scale = __expf(mold - mnew);
        mrun[mt][j] = mnew;
        float p0 = __expf(s0 - mnew);
        float p1 = __expf(s1 - mnew);
        lrun[mt][j] = lrun[mt][j] * scale + p0 + p1;
#pragma unroll
        for (int dd = 0; dd < 4; ++dd) acc[mt][dd][j] *= scale;
        p_lds[wid][mt * 16 + g * 4 + j][c] = f2bf(p0);
        p_lds[wid][mt * 16 + g * 4 + j][16 + c] = f2bf(p1);
      }
    }
    __syncthreads();
#pragma unroll
    for (int mt = 0; mt < 2; ++mt) {
      short8 pa = *(const short8*)(&p_lds[wid][mt * 16 + c][g * 8]);
#pragma unroll
      for (int dd = 0; dd < 4; ++dd) {
        short8 bv = *(const short8*)(&v_lds[dd * 16 + c][g * 8]);
        acc[mt][dd] = __builtin_amdgcn_mfma_f32_16x16x32_bf16(pa, bv, acc[mt][dd], 0, 0, 0);
      }
    }
  }
  float* ob = out + ((size_t)nh * T + (size_t)b * 128 + (size_t)wid * 32) * D;
#pragma unroll
  for (int mt = 0; mt < 2; ++mt)
#pragma unroll
    for (int j = 0; j < 4; ++j) {
      float l = lrun[mt][j];
      l += __shfl_xor(l, 1);
      l += __shfl_xor(l, 2);
      l += __shfl_xor(l, 4);
      l += __shfl_xor(l, 8);
      float inv = 1.f / l;
      int row = mt * 16 + g * 4 + j;
#pragma unroll
      for (int dd = 0; dd < 4; ++dd)
        ob[(size_t)row * D + dd * 16 + c] = acc[mt][dd][j] * inv;
    }
}

extern "C" void kernel_launch(void* const* d_in, const int* in_sizes, int n_in,
                              void* d_out, int out_size, void* d_ws, size_t ws_size,
                              hipStream_t stream) {
  const float* q  = (const float*)d_in[0];
  const float* k  = (const float*)d_in[1];
  const float* v  = (const float*)d_in[2];
  const float* am = (const float*)d_in[3];
  const float* sk = (const float*)d_in[4];
  const float* sv = (const float*)d_in[5];
  const float* sm = (const float*)d_in[6];
  const float* gk = (const float*)d_in[7];
  const float* gv = (const float*)d_in[8];
  const float* gm = (const float*)d_in[9];
  float* out = (float*)d_out;

  size_t off = 0;
  char* base = (char*)d_ws;
  auto alloc = [&](size_t bytes) { void* p = base + off; off += bytes; return p; };
  short* KL  = (short*)alloc(13369344);  // [24][4352][64] bf16 (pre-scaled)
  short* VTL = (short*)alloc(13369344);  // [24][64][4352]
  short* KS  = (short*)alloc(4128768);   // [24][1344][64]
  short* VTS = (short*)alloc(4128768);   // [24][64][1344]
  short* KG  = (short*)alloc(196608);    // [24][64][64]
  short* VTG = (short*)alloc(196608);    // [24][64][64]
  float* AM2 = (float*)alloc(34816);     // [2][4352]
  float* SM2 = (float*)alloc(10752);     // [2][1344]
  float* GM2 = (float*)alloc(512);       // [2][64]

  if (off <= ws_size) {
    hipLaunchKernelGGL(prepass_all, dim3(6525), dim3(256), 0, stream,
                       k, sk, gk, v, sv, gv, KL, KS, KG, VTL, VTS, VTG,
                       am, sm, gm, AM2, SM2, GM2);
    hipLaunchKernelGGL(lsg_attn13, dim3(768), dim3(256), 0, stream,
                       KL, VTL, KS, VTS, KG, VTG, AM2, SM2, GM2, q, out);
  } else {
    hipLaunchKernelGGL(lsg_attn_fb, dim3(768), dim3(256), 0, stream,
                       q, k, v, am, sk, sv, sm, gk, gv, gm, out);
  }
}